// Round 1
// baseline (1591.655 us; speedup 1.0000x reference)
//
#include <hip/hip_runtime.h>
#include <hip/hip_bf16.h>

#define N_NODES 50000
#define N_EDGES 800000
#define IN_DIM  256
#define OUT_DIM 64

// ---------------------------------------------------------------------------
// edge_index dtype detection: reference says int64, but JAX default config
// demotes to int32. If int64 (little-endian, values < 50000), every odd
// 32-bit word is 0. For int32 random indices in [0,50000), P(512 odd words
// all zero) ~ 0. One thread scans 1024 words.
// ---------------------------------------------------------------------------
__global__ void detect_i64(const unsigned int* __restrict__ e, int* flag) {
    if (threadIdx.x == 0 && blockIdx.x == 0) {
        int is64 = 1;
        for (int i = 1; i < 1024; i += 2) {
            if (e[i] != 0u) { is64 = 0; break; }
        }
        flag[0] = is64;
    }
}

__device__ __forceinline__ int load_idx(const void* edges, int is64, long long i) {
    if (is64) return (int)((const long long*)edges)[i];
    return ((const int*)edges)[i];
}

// deg[n] = 1 (self-loop)
__global__ void deg_init(float* __restrict__ deg) {
    int n = blockIdx.x * 256 + threadIdx.x;
    if (n < N_NODES) deg[n] = 1.0f;
}

// deg[dst] += 1 per edge
__global__ void deg_count(const void* __restrict__ edges, const int* __restrict__ flag,
                          float* __restrict__ deg) {
    int e = blockIdx.x * 256 + threadIdx.x;
    if (e >= N_EDGES) return;
    int is64 = flag[0];
    int d = load_idx(edges, is64, (long long)N_EDGES + e);
    atomicAdd(&deg[d], 1.0f);
}

// in-place deg -> rsqrt(deg)
__global__ void dinv_kernel(float* __restrict__ deg) {
    int n = blockIdx.x * 256 + threadIdx.x;
    if (n < N_NODES) deg[n] = rsqrtf(deg[n]);
}

// ---------------------------------------------------------------------------
// H[N,64] = X[N,K] @ W[K,64]   (optionally relu(X) on load)
// Block: 256 threads, computes 32 rows. Thread (j = t&63, ms = t>>6) owns
// column j of rows {row0 + ms + 4m : m=0..7}. W chunk staged in LDS [KC][64];
// lanes read consecutive floats -> 2 lanes/bank -> conflict-free.
// X loads are wave-uniform (whole wave same row,k) -> broadcast, L1-hit.
// ---------------------------------------------------------------------------
template <int K, bool RELU>
__global__ __launch_bounds__(256) void gemm_kernel(const float* __restrict__ X,
                                                   const float* __restrict__ W,
                                                   float* __restrict__ H) {
    constexpr int KC = (K > 128) ? 128 : K;
    __shared__ float lw[KC][64];
    const int j  = threadIdx.x & 63;
    const int ms = threadIdx.x >> 6;
    const int row0 = blockIdx.x * 32;

    float acc[8] = {0.f,0.f,0.f,0.f,0.f,0.f,0.f,0.f};

    int rows[8];
#pragma unroll
    for (int m = 0; m < 8; ++m) {
        int r = row0 + ms + 4 * m;
        rows[m] = (r < N_NODES) ? r : (N_NODES - 1);  // clamp; store guarded
    }

    for (int kc = 0; kc < K; kc += KC) {
        __syncthreads();
        for (int idx = threadIdx.x; idx < KC * 64; idx += 256) {
            lw[idx >> 6][idx & 63] = W[(kc + (idx >> 6)) * 64 + (idx & 63)];
        }
        __syncthreads();

        for (int k = 0; k < KC; k += 4) {
            float w0 = lw[k + 0][j];
            float w1 = lw[k + 1][j];
            float w2 = lw[k + 2][j];
            float w3 = lw[k + 3][j];
#pragma unroll
            for (int m = 0; m < 8; ++m) {
                float4 xv = *(const float4*)&X[(long long)rows[m] * K + kc + k];
                if (RELU) {
                    xv.x = fmaxf(xv.x, 0.f); xv.y = fmaxf(xv.y, 0.f);
                    xv.z = fmaxf(xv.z, 0.f); xv.w = fmaxf(xv.w, 0.f);
                }
                acc[m] = fmaf(xv.x, w0, acc[m]);
                acc[m] = fmaf(xv.y, w1, acc[m]);
                acc[m] = fmaf(xv.z, w2, acc[m]);
                acc[m] = fmaf(xv.w, w3, acc[m]);
            }
        }
    }

#pragma unroll
    for (int m = 0; m < 8; ++m) {
        int r = row0 + ms + 4 * m;
        if (r < N_NODES) H[(long long)r * 64 + j] = acc[m];
    }
}

// out[n][j] = H[n][j] * dinv[n]^2 (self-loop) + b[j]
__global__ void agg_init(const float* __restrict__ H, const float* __restrict__ dinv,
                         const float* __restrict__ b, float* __restrict__ out) {
    int gid = blockIdx.x * 256 + threadIdx.x;
    if (gid >= N_NODES * 64) return;
    int n = gid >> 6;
    int j = gid & 63;
    float di = dinv[n];
    out[gid] = H[gid] * di * di + b[j];
}

// per edge: out[dst] += H[src] * (dinv[src]*dinv[dst]);  16 threads/edge x float4
__global__ void agg_edges(const void* __restrict__ edges, const int* __restrict__ flag,
                          const float* __restrict__ H, const float* __restrict__ dinv,
                          float* __restrict__ out) {
    long long gid = (long long)blockIdx.x * 256 + threadIdx.x;
    int e = (int)(gid >> 4);
    int q = (int)(gid & 15);
    if (e >= N_EDGES) return;
    int is64 = flag[0];
    int s = load_idx(edges, is64, e);
    int d = load_idx(edges, is64, (long long)N_EDGES + e);
    float norm = dinv[s] * dinv[d];
    float4 v = *(const float4*)&H[(long long)s * 64 + q * 4];
    float* o = &out[(long long)d * 64 + q * 4];
    atomicAdd(o + 0, v.x * norm);
    atomicAdd(o + 1, v.y * norm);
    atomicAdd(o + 2, v.z * norm);
    atomicAdd(o + 3, v.w * norm);
}

__global__ void relu_kernel(float* __restrict__ out) {
    int gid = blockIdx.x * 256 + threadIdx.x;
    if (gid < N_NODES * 64) out[gid] = fmaxf(out[gid], 0.f);
}

extern "C" void kernel_launch(void* const* d_in, const int* in_sizes, int n_in,
                              void* d_out, int out_size, void* d_ws, size_t ws_size,
                              hipStream_t stream) {
    const float* feat = (const float*)d_in[0];
    const float* W1   = (const float*)d_in[1];
    const float* b1   = (const float*)d_in[2];
    const float* W2   = (const float*)d_in[3];
    const float* b2   = (const float*)d_in[4];
    const void*  edges = d_in[5];
    float* out = (float*)d_out;

    char* ws = (char*)d_ws;
    int*   flag = (int*)ws;                      // 256 B reserved
    float* dinv = (float*)(ws + 256);            // 50000 f32
    float* H    = (float*)(ws + 262144);         // 50000*64 f32 = 12.8 MB

    const int NB_N  = (N_NODES + 255) / 256;
    const int NB_E  = (N_EDGES + 255) / 256;
    const int NB_G  = (N_NODES + 31) / 32;
    const int NB_NO = (N_NODES * 64 + 255) / 256;
    const int NB_AG = (int)(((long long)N_EDGES * 16) / 256);  // 50000 exactly

    detect_i64<<<1, 64, 0, stream>>>((const unsigned int*)edges, flag);
    deg_init<<<NB_N, 256, 0, stream>>>(dinv);
    deg_count<<<NB_E, 256, 0, stream>>>(edges, flag, dinv);
    dinv_kernel<<<NB_N, 256, 0, stream>>>(dinv);

    // Layer 1
    gemm_kernel<IN_DIM, false><<<NB_G, 256, 0, stream>>>(feat, W1, H);
    agg_init<<<NB_NO, 256, 0, stream>>>(H, dinv, b1, out);
    agg_edges<<<NB_AG, 256, 0, stream>>>(edges, flag, H, dinv, out);
    // out now holds pre-relu z1; GEMM2 applies relu on load.

    // Layer 2
    gemm_kernel<OUT_DIM, true><<<NB_G, 256, 0, stream>>>(out, W2, H);
    agg_init<<<NB_NO, 256, 0, stream>>>(H, dinv, b2, out);
    agg_edges<<<NB_AG, 256, 0, stream>>>(edges, flag, H, dinv, out);
    relu_kernel<<<NB_NO, 256, 0, stream>>>(out);
}

// Round 2
// 459.691 us; speedup vs baseline: 3.4624x; 3.4624x over previous
//
#include <hip/hip_runtime.h>
#include <hip/hip_bf16.h>

#define N_NODES 50000
#define N_EDGES 800000
#define IN_DIM  256
#define OUT_DIM 64

// ---------------------------------------------------------------------------
// edge_index dtype detection: reference says int64, but JAX default config
// demotes to int32. If int64 (little-endian, values < 50000), every odd
// 32-bit word is 0. One thread scans 1024 words.
// ---------------------------------------------------------------------------
__global__ void detect_i64(const unsigned int* __restrict__ e, int* flag) {
    if (threadIdx.x == 0 && blockIdx.x == 0) {
        int is64 = 1;
        for (int i = 1; i < 1024; i += 2) {
            if (e[i] != 0u) { is64 = 0; break; }
        }
        flag[0] = is64;
    }
}

__device__ __forceinline__ int load_idx(const void* edges, int is64, long long i) {
    if (is64) return (int)((const long long*)edges)[i];
    return ((const int*)edges)[i];
}

__global__ void zero_cnt(int* __restrict__ cnt) {
    int n = blockIdx.x * 256 + threadIdx.x;
    if (n < N_NODES) cnt[n] = 0;
}

// cnt[dst] += 1 per edge (int atomics, L2-side, cheap)
__global__ void deg_count(const void* __restrict__ edges, const int* __restrict__ flag,
                          int* __restrict__ cnt) {
    int e = blockIdx.x * 256 + threadIdx.x;
    if (e >= N_EDGES) return;
    int is64 = flag[0];
    int d = load_idx(edges, is64, (long long)N_EDGES + e);
    atomicAdd(&cnt[d], 1);
}

// dinv[n] = rsqrt(cnt[n] + 1)   (+1 = self loop)
__global__ void dinv_kernel(const int* __restrict__ cnt, float* __restrict__ dinv) {
    int n = blockIdx.x * 256 + threadIdx.x;
    if (n < N_NODES) dinv[n] = rsqrtf((float)(cnt[n] + 1));
}

// Exclusive prefix sum of cnt[0..N) -> off[0..N], single 1024-thread block.
__global__ void scan_kernel(const int* __restrict__ cnt, int* __restrict__ off) {
    __shared__ int smem[1024];
    __shared__ int running_s;
    if (threadIdx.x == 0) running_s = 0;
    __syncthreads();
    for (int base = 0; base < N_NODES; base += 1024) {
        int i = base + threadIdx.x;
        int v = (i < N_NODES) ? cnt[i] : 0;
        smem[threadIdx.x] = v;
        __syncthreads();
        for (int s = 1; s < 1024; s <<= 1) {
            int t = 0;
            if (threadIdx.x >= s) t = smem[threadIdx.x - s];
            __syncthreads();
            if (threadIdx.x >= s) smem[threadIdx.x] += t;
            __syncthreads();
        }
        int incl = smem[threadIdx.x];
        int run = running_s;
        if (i < N_NODES) off[i] = run + incl - v;
        __syncthreads();
        if (threadIdx.x == 1023) running_s = run + incl;
        __syncthreads();
    }
    if (threadIdx.x == 0) off[N_NODES] = running_s;
}

__global__ void cursor_init(const int* __restrict__ off, int* __restrict__ cursor) {
    int n = blockIdx.x * 256 + threadIdx.x;
    if (n < N_NODES) cursor[n] = off[n];
}

// Bucket edges by dst: csr[pos] = (src, norm)
__global__ void scatter_kernel(const void* __restrict__ edges, const int* __restrict__ flag,
                               const float* __restrict__ dinv, int* __restrict__ cursor,
                               int2* __restrict__ csr) {
    int e = blockIdx.x * 256 + threadIdx.x;
    if (e >= N_EDGES) return;
    int is64 = flag[0];
    int s = load_idx(edges, is64, e);
    int d = load_idx(edges, is64, (long long)N_EDGES + e);
    float norm = dinv[s] * dinv[d];
    int pos = atomicAdd(&cursor[d], 1);
    csr[pos] = make_int2(s, __float_as_int(norm));
}

// ---------------------------------------------------------------------------
// H[N,64] = X[N,K] @ W[K,64]. 256 thr = 32 rows/block; thread (j=t&63,
// ms=t>>6) owns col j of rows {row0+ms+4m}. W chunk in LDS (conflict-free).
// ---------------------------------------------------------------------------
template <int K>
__global__ __launch_bounds__(256) void gemm_kernel(const float* __restrict__ X,
                                                   const float* __restrict__ W,
                                                   float* __restrict__ H) {
    constexpr int KC = (K > 128) ? 128 : K;
    __shared__ float lw[KC][64];
    const int j  = threadIdx.x & 63;
    const int ms = threadIdx.x >> 6;
    const int row0 = blockIdx.x * 32;

    float acc[8] = {0.f,0.f,0.f,0.f,0.f,0.f,0.f,0.f};

    int rows[8];
#pragma unroll
    for (int m = 0; m < 8; ++m) {
        int r = row0 + ms + 4 * m;
        rows[m] = (r < N_NODES) ? r : (N_NODES - 1);
    }

    for (int kc = 0; kc < K; kc += KC) {
        __syncthreads();
        for (int idx = threadIdx.x; idx < KC * 64; idx += 256) {
            lw[idx >> 6][idx & 63] = W[(kc + (idx >> 6)) * 64 + (idx & 63)];
        }
        __syncthreads();

        for (int k = 0; k < KC; k += 4) {
            float w0 = lw[k + 0][j];
            float w1 = lw[k + 1][j];
            float w2 = lw[k + 2][j];
            float w3 = lw[k + 3][j];
#pragma unroll
            for (int m = 0; m < 8; ++m) {
                float4 xv = *(const float4*)&X[(long long)rows[m] * K + kc + k];
                acc[m] = fmaf(xv.x, w0, acc[m]);
                acc[m] = fmaf(xv.y, w1, acc[m]);
                acc[m] = fmaf(xv.z, w2, acc[m]);
                acc[m] = fmaf(xv.w, w3, acc[m]);
            }
        }
    }

#pragma unroll
    for (int m = 0; m < 8; ++m) {
        int r = row0 + ms + 4 * m;
        if (r < N_NODES) H[(long long)r * 64 + j] = acc[m];
    }
}

// ---------------------------------------------------------------------------
// Gather-aggregate: one wave per dst node, lane j = column j.
// acc = H[d]*dinv[d]^2 + b  +  sum_{(s,norm) in csr[d]} H[s]*norm;  relu.
// Edge meta loaded coalesced (64 int2/wave) then broadcast via shfl.
// ---------------------------------------------------------------------------
__global__ __launch_bounds__(256) void agg_csr(const float* __restrict__ H,
                                               const float* __restrict__ dinv,
                                               const float* __restrict__ b,
                                               const int* __restrict__ off,
                                               const int2* __restrict__ csr,
                                               float* __restrict__ out) {
    int wid  = (blockIdx.x * 256 + threadIdx.x) >> 6;
    int lane = threadIdx.x & 63;
    if (wid >= N_NODES) return;
    float dd = dinv[wid];
    float acc = H[(long long)wid * 64 + lane] * dd * dd + b[lane];
    int beg = off[wid], end = off[wid + 1];
    for (int k0 = beg; k0 < end; k0 += 64) {
        int myk = k0 + lane;
        int2 ev = (myk < end) ? csr[myk] : make_int2(0, 0);
        int cnt = min(64, end - k0);
        for (int i = 0; i < cnt; ++i) {
            int   s  = __shfl(ev.x, i);
            float nm = __shfl(__int_as_float(ev.y), i);
            acc = fmaf(H[(long long)s * 64 + lane], nm, acc);
        }
    }
    out[(long long)wid * 64 + lane] = fmaxf(acc, 0.f);
}

extern "C" void kernel_launch(void* const* d_in, const int* in_sizes, int n_in,
                              void* d_out, int out_size, void* d_ws, size_t ws_size,
                              hipStream_t stream) {
    const float* feat = (const float*)d_in[0];
    const float* W1   = (const float*)d_in[1];
    const float* b1   = (const float*)d_in[2];
    const float* W2   = (const float*)d_in[3];
    const float* b2   = (const float*)d_in[4];
    const void*  edges = d_in[5];
    float* out = (float*)d_out;

    char* ws = (char*)d_ws;
    int*   flag   = (int*)ws;                         // 256 B
    float* dinv   = (float*)(ws + 256);               // 200 KB
    int*   cnt    = (int*)(ws + 256 + 200704);        // 200 KB
    int*   off    = (int*)(ws + 256 + 2 * 200704);    // 200 KB (+1 entry)
    int*   cursor = (int*)(ws + 256 + 3 * 200704);    // 200 KB
    int2*  csr    = (int2*)(ws + 256 + 4 * 200704);   // 6.4 MB
    float* H      = (float*)(ws + 256 + 4 * 200704 + (size_t)N_EDGES * 8);  // 12.8 MB

    const int NB_N  = (N_NODES + 255) / 256;
    const int NB_E  = (N_EDGES + 255) / 256;
    const int NB_G  = (N_NODES + 31) / 32;
    const int NB_W  = (N_NODES * 64 + 255) / 256;   // 1 wave per node

    detect_i64<<<1, 64, 0, stream>>>((const unsigned int*)edges, flag);
    zero_cnt<<<NB_N, 256, 0, stream>>>(cnt);
    deg_count<<<NB_E, 256, 0, stream>>>(edges, flag, cnt);
    dinv_kernel<<<NB_N, 256, 0, stream>>>(cnt, dinv);
    scan_kernel<<<1, 1024, 0, stream>>>(cnt, off);
    cursor_init<<<NB_N, 256, 0, stream>>>(off, cursor);
    scatter_kernel<<<NB_E, 256, 0, stream>>>(edges, flag, dinv, cursor, csr);

    // Layer 1: H = feat @ W1; out = relu(agg(H) + b1)
    gemm_kernel<IN_DIM><<<NB_G, 256, 0, stream>>>(feat, W1, H);
    agg_csr<<<NB_W, 256, 0, stream>>>(H, dinv, b1, off, csr, out);

    // Layer 2: H = out @ W2; out = relu(agg(H) + b2)
    gemm_kernel<OUT_DIM><<<NB_G, 256, 0, stream>>>(out, W2, H);
    agg_csr<<<NB_W, 256, 0, stream>>>(H, dinv, b2, off, csr, out);
}

// Round 3
// 220.057 us; speedup vs baseline: 7.2329x; 2.0890x over previous
//
#include <hip/hip_runtime.h>
#include <hip/hip_bf16.h>

#define N_NODES 50000
#define N_EDGES 800000
#define IN_DIM  256
#define OUT_DIM 64
#define NCH     49   // ceil(50000/1024) chunks for the scan

// ---------------------------------------------------------------------------
// edge_index dtype probe (int64 vs int32): values < 50000, so if int64 every
// odd 32-bit word is 0 over the first 512 pairs.
// ---------------------------------------------------------------------------
__global__ void detect_i64(const unsigned int* __restrict__ e, int* flag) {
    if (threadIdx.x == 0 && blockIdx.x == 0) {
        int is64 = 1;
        for (int i = 1; i < 1024; i += 2) {
            if (e[i] != 0u) { is64 = 0; break; }
        }
        flag[0] = is64;
    }
}

__device__ __forceinline__ int load_idx(const void* edges, int is64, long long i) {
    if (is64) return (int)((const long long*)edges)[i];
    return ((const int*)edges)[i];
}

__global__ void zero_cnt(int* __restrict__ cnt) {
    int n = blockIdx.x * 256 + threadIdx.x;
    if (n < N_NODES) cnt[n] = 0;
}

__global__ void deg_count(const void* __restrict__ edges, const int* __restrict__ flag,
                          int* __restrict__ cnt) {
    int e = blockIdx.x * 256 + threadIdx.x;
    if (e >= N_EDGES) return;
    int is64 = flag[0];
    int d = load_idx(edges, is64, (long long)N_EDGES + e);
    atomicAdd(&cnt[d], 1);
}

__global__ void dinv_kernel(const int* __restrict__ cnt, float* __restrict__ dinv) {
    int n = blockIdx.x * 256 + threadIdx.x;
    if (n < N_NODES) dinv[n] = rsqrtf((float)(cnt[n] + 1));
}

// --------------------- hierarchical exclusive scan -------------------------
// scan_local: per-1024 chunk exclusive scan into off[], chunk total -> partial[b]
__global__ __launch_bounds__(1024) void scan_local(const int* __restrict__ cnt,
                                                   int* __restrict__ off,
                                                   int* __restrict__ partial) {
    __shared__ int smem[1024];
    int i = blockIdx.x * 1024 + threadIdx.x;
    int v = (i < N_NODES) ? cnt[i] : 0;
    smem[threadIdx.x] = v;
    __syncthreads();
    for (int s = 1; s < 1024; s <<= 1) {
        int t = 0;
        if (threadIdx.x >= s) t = smem[threadIdx.x - s];
        __syncthreads();
        if (threadIdx.x >= s) smem[threadIdx.x] += t;
        __syncthreads();
    }
    int incl = smem[threadIdx.x];
    if (i < N_NODES) off[i] = incl - v;
    if (threadIdx.x == 1023) partial[blockIdx.x] = incl;
}

// scan_mid: 1 block / 64 lanes: exclusive scan of NCH partials; total -> partial[63]
__global__ void scan_mid(int* __restrict__ partial) {
    int lane = threadIdx.x;
    int v = (lane < NCH) ? partial[lane] : 0;
    int orig = v;
    for (int s = 1; s < 64; s <<= 1) {
        int t = __shfl_up(v, s);
        if (lane >= s) v += t;
    }
    if (lane < NCH) partial[lane] = v - orig;
    if (lane == 63) partial[63] = v;   // grand total (NCH < 63)
}

// scan_add: off[i] += chunk base; one thread writes off[N_NODES] = total
__global__ __launch_bounds__(1024) void scan_add(int* __restrict__ off,
                                                 const int* __restrict__ partial) {
    int i = blockIdx.x * 1024 + threadIdx.x;
    if (i < N_NODES) off[i] += partial[blockIdx.x];
    if (i == 0) off[N_NODES] = partial[63];
}

__global__ void cursor_init(const int* __restrict__ off, int* __restrict__ cursor) {
    int n = blockIdx.x * 256 + threadIdx.x;
    if (n < N_NODES) cursor[n] = off[n];
}

// Bucket edges by dst: csr[pos] = (src, norm)
__global__ void scatter_kernel(const void* __restrict__ edges, const int* __restrict__ flag,
                               const float* __restrict__ dinv, int* __restrict__ cursor,
                               int2* __restrict__ csr) {
    int e = blockIdx.x * 256 + threadIdx.x;
    if (e >= N_EDGES) return;
    int is64 = flag[0];
    int s = load_idx(edges, is64, e);
    int d = load_idx(edges, is64, (long long)N_EDGES + e);
    float norm = dinv[s] * dinv[d];
    int pos = atomicAdd(&cursor[d], 1);
    csr[pos] = make_int2(s, __float_as_int(norm));
}

// ---------------------------------------------------------------------------
// H[N,64] = X[N,K] @ W[K,64].
// W fully staged in LDS (K*64 floats) -> no barriers in k-loop.
// 256 threads, BM=128 rows/block. Lane: cg=lane&15 (4 cols), rg=lane>>4;
// thread owns 8 rows x 4 cols. Per 4-k step: 8 global b128 (X rows,
// independent -> pipelined), 4 LDS b128 (2-way bank = free), 128 FMA.
// ---------------------------------------------------------------------------
#define FMA4(av, bv, ai)                                  \
    acc[ai][0] = fmaf(av, bv.x, acc[ai][0]);              \
    acc[ai][1] = fmaf(av, bv.y, acc[ai][1]);              \
    acc[ai][2] = fmaf(av, bv.z, acc[ai][2]);              \
    acc[ai][3] = fmaf(av, bv.w, acc[ai][3]);

template <int K>
__global__ __launch_bounds__(256) void gemm_kernel(const float* __restrict__ X,
                                                   const float* __restrict__ W,
                                                   float* __restrict__ H) {
    __shared__ float wlds[K][64];
    for (int idx = threadIdx.x; idx < K * 16; idx += 256) {
        ((float4*)wlds)[idx] = ((const float4*)W)[idx];
    }
    __syncthreads();

    const int lane = threadIdx.x & 63;
    const int wave = threadIdx.x >> 6;
    const int cg = lane & 15;
    const int rg = lane >> 4;
    const int c0 = cg * 4;
    const int r0 = blockIdx.x * 128 + (wave * 4 + rg) * 8;

    const float* xrow[8];
#pragma unroll
    for (int i = 0; i < 8; ++i) {
        int r = r0 + i;
        if (r >= N_NODES) r = N_NODES - 1;   // clamp; stores guarded
        xrow[i] = X + (size_t)r * K;
    }

    float acc[8][4] = {};

#pragma unroll 2
    for (int k = 0; k < K; k += 4) {
        float4 a[8];
#pragma unroll
        for (int i = 0; i < 8; ++i) a[i] = *(const float4*)(xrow[i] + k);
        float4 b0 = *(const float4*)&wlds[k + 0][c0];
        float4 b1 = *(const float4*)&wlds[k + 1][c0];
        float4 b2 = *(const float4*)&wlds[k + 2][c0];
        float4 b3 = *(const float4*)&wlds[k + 3][c0];
#pragma unroll
        for (int i = 0; i < 8; ++i) {
            FMA4(a[i].x, b0, i)
            FMA4(a[i].y, b1, i)
            FMA4(a[i].z, b2, i)
            FMA4(a[i].w, b3, i)
        }
    }

#pragma unroll
    for (int i = 0; i < 8; ++i) {
        int r = r0 + i;
        if (r < N_NODES) {
            float4 o = make_float4(acc[i][0], acc[i][1], acc[i][2], acc[i][3]);
            *(float4*)&H[(size_t)r * 64 + c0] = o;
        }
    }
}

// ---------------------------------------------------------------------------
// Gather-aggregate: one wave per dst node, lane = column. Edges in batches
// of 8: 8 independent H-row loads in flight, then 8 FMAs.
// ---------------------------------------------------------------------------
__global__ __launch_bounds__(256) void agg_csr(const float* __restrict__ H,
                                               const float* __restrict__ dinv,
                                               const float* __restrict__ b,
                                               const int* __restrict__ off,
                                               const int2* __restrict__ csr,
                                               float* __restrict__ out) {
    int wid  = (blockIdx.x * 256 + threadIdx.x) >> 6;
    int lane = threadIdx.x & 63;
    if (wid >= N_NODES) return;
    float dd = dinv[wid];
    float acc = H[(size_t)wid * 64 + lane] * dd * dd + b[lane];
    int beg = off[wid], end = off[wid + 1];
    for (int k0 = beg; k0 < end; k0 += 64) {
        int myk = k0 + lane;
        int2 ev = (myk < end) ? csr[myk] : make_int2(0, 0);
        int cnt = min(64, end - k0);
        int i = 0;
        for (; i + 8 <= cnt; i += 8) {
            float v[8], nm[8];
#pragma unroll
            for (int jj = 0; jj < 8; ++jj) {
                int s  = __shfl(ev.x, i + jj);
                nm[jj] = __shfl(__int_as_float(ev.y), i + jj);
                v[jj]  = H[(size_t)s * 64 + lane];
            }
#pragma unroll
            for (int jj = 0; jj < 8; ++jj) acc = fmaf(v[jj], nm[jj], acc);
        }
        for (; i < cnt; ++i) {
            int   s  = __shfl(ev.x, i);
            float nm = __shfl(__int_as_float(ev.y), i);
            acc = fmaf(H[(size_t)s * 64 + lane], nm, acc);
        }
    }
    out[(size_t)wid * 64 + lane] = fmaxf(acc, 0.f);
}

extern "C" void kernel_launch(void* const* d_in, const int* in_sizes, int n_in,
                              void* d_out, int out_size, void* d_ws, size_t ws_size,
                              hipStream_t stream) {
    const float* feat = (const float*)d_in[0];
    const float* W1   = (const float*)d_in[1];
    const float* b1   = (const float*)d_in[2];
    const float* W2   = (const float*)d_in[3];
    const float* b2   = (const float*)d_in[4];
    const void*  edges = d_in[5];
    float* out = (float*)d_out;

    char* ws = (char*)d_ws;
    const size_t SZ_N = 200704;  // >= 50001 ints
    int*   flag    = (int*)ws;                       // 256 B
    int*   partial = (int*)(ws + 256);               // 64 ints
    float* dinv    = (float*)(ws + 1024);
    int*   cnt     = (int*)(ws + 1024 + SZ_N);
    int*   off     = (int*)(ws + 1024 + 2 * SZ_N);
    int*   cursor  = (int*)(ws + 1024 + 3 * SZ_N);
    int2*  csr     = (int2*)(ws + 1024 + 4 * SZ_N);               // 6.4 MB
    float* H       = (float*)(ws + 1024 + 4 * SZ_N + (size_t)N_EDGES * 8);  // 12.8 MB

    const int NB_N = (N_NODES + 255) / 256;
    const int NB_E = (N_EDGES + 255) / 256;
    const int NB_G = (N_NODES + 127) / 128;
    const int NB_W = (N_NODES * 64 + 255) / 256;

    detect_i64<<<1, 64, 0, stream>>>((const unsigned int*)edges, flag);
    zero_cnt<<<NB_N, 256, 0, stream>>>(cnt);
    deg_count<<<NB_E, 256, 0, stream>>>(edges, flag, cnt);
    dinv_kernel<<<NB_N, 256, 0, stream>>>(cnt, dinv);
    scan_local<<<NCH, 1024, 0, stream>>>(cnt, off, partial);
    scan_mid<<<1, 64, 0, stream>>>(partial);
    scan_add<<<NCH, 1024, 0, stream>>>(off, partial);
    cursor_init<<<NB_N, 256, 0, stream>>>(off, cursor);
    scatter_kernel<<<NB_E, 256, 0, stream>>>(edges, flag, dinv, cursor, csr);

    // Layer 1
    gemm_kernel<IN_DIM><<<NB_G, 256, 0, stream>>>(feat, W1, H);
    agg_csr<<<NB_W, 256, 0, stream>>>(H, dinv, b1, off, csr, out);

    // Layer 2 (out holds relu'd z1)
    gemm_kernel<OUT_DIM><<<NB_G, 256, 0, stream>>>(out, W2, H);
    agg_csr<<<NB_W, 256, 0, stream>>>(H, dinv, b2, off, csr, out);
}

// Round 4
// 209.380 us; speedup vs baseline: 7.6018x; 1.0510x over previous
//
#include <hip/hip_runtime.h>
#include <hip/hip_bf16.h>

#define N_NODES 50000
#define N_EDGES 800000
#define IN_DIM  256
#define OUT_DIM 64
#define NCH     49   // ceil(50000/1024) chunks for the scan

// ---------------------------------------------------------------------------
// init: zero cnt[] everywhere; block 0 thread 0 also probes edge dtype.
// int64 little-endian values < 50000 -> every odd 32-bit word is 0.
// ---------------------------------------------------------------------------
__global__ void init_kernel(const unsigned int* __restrict__ e, int* __restrict__ cnt,
                            int* __restrict__ flag) {
    int n = blockIdx.x * 256 + threadIdx.x;
    if (n < N_NODES) cnt[n] = 0;
    if (n == 0) {
        int is64 = 1;
        for (int i = 1; i < 1024; i += 2) {
            if (e[i] != 0u) { is64 = 0; break; }
        }
        flag[0] = is64;
    }
}

__device__ __forceinline__ int load_idx(const void* edges, int is64, long long i) {
    if (is64) return (int)((const long long*)edges)[i];
    return ((const int*)edges)[i];
}

__global__ void deg_count(const void* __restrict__ edges, const int* __restrict__ flag,
                          int* __restrict__ cnt) {
    int e = blockIdx.x * 256 + threadIdx.x;
    if (e >= N_EDGES) return;
    int is64 = flag[0];
    int d = load_idx(edges, is64, (long long)N_EDGES + e);
    atomicAdd(&cnt[d], 1);
}

// --------------------- hierarchical exclusive scan -------------------------
// scan_local: per-1024 chunk exclusive scan into off[]; chunk total -> partial[b];
// also dinv[i] = rsqrt(cnt[i]+1).
__global__ __launch_bounds__(1024) void scan_local(const int* __restrict__ cnt,
                                                   int* __restrict__ off,
                                                   int* __restrict__ partial,
                                                   float* __restrict__ dinv) {
    __shared__ int smem[1024];
    int i = blockIdx.x * 1024 + threadIdx.x;
    int v = (i < N_NODES) ? cnt[i] : 0;
    if (i < N_NODES) dinv[i] = rsqrtf((float)(v + 1));
    smem[threadIdx.x] = v;
    __syncthreads();
    for (int s = 1; s < 1024; s <<= 1) {
        int t = 0;
        if (threadIdx.x >= s) t = smem[threadIdx.x - s];
        __syncthreads();
        if (threadIdx.x >= s) smem[threadIdx.x] += t;
        __syncthreads();
    }
    int incl = smem[threadIdx.x];
    if (i < N_NODES) off[i] = incl - v;
    if (threadIdx.x == 1023) partial[blockIdx.x] = incl;
}

// scan_mid: 64 lanes: exclusive scan of NCH partials; total -> partial[63]
__global__ void scan_mid(int* __restrict__ partial) {
    int lane = threadIdx.x;
    int v = (lane < NCH) ? partial[lane] : 0;
    int orig = v;
    for (int s = 1; s < 64; s <<= 1) {
        int t = __shfl_up(v, s);
        if (lane >= s) v += t;
    }
    if (lane < NCH) partial[lane] = v - orig;
    if (lane == 63) partial[63] = v;   // grand total (NCH <= 63)
}

// scan_add: off[i] += chunk base; cursor[i] = off[i]; off[N] = total
__global__ __launch_bounds__(1024) void scan_add(int* __restrict__ off,
                                                 const int* __restrict__ partial,
                                                 int* __restrict__ cursor) {
    int i = blockIdx.x * 1024 + threadIdx.x;
    if (i < N_NODES) {
        int o = off[i] + partial[blockIdx.x];
        off[i] = o;
        cursor[i] = o;
    }
    if (i == 0) off[N_NODES] = partial[63];
}

// Bucket edges by dst: csr[pos] = (src, norm)
__global__ void scatter_kernel(const void* __restrict__ edges, const int* __restrict__ flag,
                               const float* __restrict__ dinv, int* __restrict__ cursor,
                               int2* __restrict__ csr) {
    int e = blockIdx.x * 256 + threadIdx.x;
    if (e >= N_EDGES) return;
    int is64 = flag[0];
    int s = load_idx(edges, is64, e);
    int d = load_idx(edges, is64, (long long)N_EDGES + e);
    float norm = dinv[s] * dinv[d];
    int pos = atomicAdd(&cursor[d], 1);
    csr[pos] = make_int2(s, __float_as_int(norm));
}

// ---------------------------------------------------------------------------
// H[N,64] = X[N,K] @ W[K,64].
// BM=64 rows/block, 256 threads: thread (cg=lane&15, rg=lane>>4, wave) owns
// 4 rows x 4 cols. W staged in LDS in KC=128 chunks (32 KB max) ->
// >=3 blocks/CU resident at grid=782. Per 4-k step: 4 global b128 (X, 16-lane
// broadcast), 4 LDS b128 (2-way bank = free), 64 FMA.
// ---------------------------------------------------------------------------
#define FMA4(av, bv, ai)                                  \
    acc[ai][0] = fmaf(av, bv.x, acc[ai][0]);              \
    acc[ai][1] = fmaf(av, bv.y, acc[ai][1]);              \
    acc[ai][2] = fmaf(av, bv.z, acc[ai][2]);              \
    acc[ai][3] = fmaf(av, bv.w, acc[ai][3]);

template <int K>
__global__ __launch_bounds__(256) void gemm_kernel(const float* __restrict__ X,
                                                   const float* __restrict__ W,
                                                   float* __restrict__ H) {
    constexpr int KC = (K > 128) ? 128 : K;
    __shared__ float wlds[KC][64];

    const int lane = threadIdx.x & 63;
    const int wave = threadIdx.x >> 6;
    const int cg = lane & 15;
    const int rg = lane >> 4;
    const int c0 = cg * 4;
    const int r0 = blockIdx.x * 64 + (wave * 4 + rg) * 4;

    const float* xrow[4];
#pragma unroll
    for (int i = 0; i < 4; ++i) {
        int r = r0 + i;
        if (r >= N_NODES) r = N_NODES - 1;   // clamp; stores guarded
        xrow[i] = X + (size_t)r * K;
    }

    float acc[4][4] = {};

    for (int kc = 0; kc < K; kc += KC) {
        __syncthreads();
        for (int idx = threadIdx.x; idx < KC * 16; idx += 256) {
            ((float4*)wlds)[idx] = ((const float4*)(W + kc * 64))[idx];
        }
        __syncthreads();

#pragma unroll 2
        for (int k = 0; k < KC; k += 4) {
            float4 a[4];
#pragma unroll
            for (int i = 0; i < 4; ++i) a[i] = *(const float4*)(xrow[i] + kc + k);
            float4 b0 = *(const float4*)&wlds[k + 0][c0];
            float4 b1 = *(const float4*)&wlds[k + 1][c0];
            float4 b2 = *(const float4*)&wlds[k + 2][c0];
            float4 b3 = *(const float4*)&wlds[k + 3][c0];
#pragma unroll
            for (int i = 0; i < 4; ++i) {
                FMA4(a[i].x, b0, i)
                FMA4(a[i].y, b1, i)
                FMA4(a[i].z, b2, i)
                FMA4(a[i].w, b3, i)
            }
        }
    }

#pragma unroll
    for (int i = 0; i < 4; ++i) {
        int r = r0 + i;
        if (r < N_NODES) {
            float4 o = make_float4(acc[i][0], acc[i][1], acc[i][2], acc[i][3]);
            *(float4*)&H[(size_t)r * 64 + c0] = o;
        }
    }
}

// ---------------------------------------------------------------------------
// Gather-aggregate: one wave per dst node, lane = column. Edges in batches
// of 8: 8 independent H-row loads in flight, then 8 FMAs.
// ---------------------------------------------------------------------------
__global__ __launch_bounds__(256) void agg_csr(const float* __restrict__ H,
                                               const float* __restrict__ dinv,
                                               const float* __restrict__ b,
                                               const int* __restrict__ off,
                                               const int2* __restrict__ csr,
                                               float* __restrict__ out) {
    int wid  = (blockIdx.x * 256 + threadIdx.x) >> 6;
    int lane = threadIdx.x & 63;
    if (wid >= N_NODES) return;
    float dd = dinv[wid];
    float acc = H[(size_t)wid * 64 + lane] * dd * dd + b[lane];
    int beg = off[wid], end = off[wid + 1];
    for (int k0 = beg; k0 < end; k0 += 64) {
        int myk = k0 + lane;
        int2 ev = (myk < end) ? csr[myk] : make_int2(0, 0);
        int cnt = min(64, end - k0);
        int i = 0;
        for (; i + 8 <= cnt; i += 8) {
            float v[8], nm[8];
#pragma unroll
            for (int jj = 0; jj < 8; ++jj) {
                int s  = __shfl(ev.x, i + jj);
                nm[jj] = __shfl(__int_as_float(ev.y), i + jj);
                v[jj]  = H[(size_t)s * 64 + lane];
            }
#pragma unroll
            for (int jj = 0; jj < 8; ++jj) acc = fmaf(v[jj], nm[jj], acc);
        }
        for (; i < cnt; ++i) {
            int   s  = __shfl(ev.x, i);
            float nm = __shfl(__int_as_float(ev.y), i);
            acc = fmaf(H[(size_t)s * 64 + lane], nm, acc);
        }
    }
    out[(size_t)wid * 64 + lane] = fmaxf(acc, 0.f);
}

extern "C" void kernel_launch(void* const* d_in, const int* in_sizes, int n_in,
                              void* d_out, int out_size, void* d_ws, size_t ws_size,
                              hipStream_t stream) {
    const float* feat = (const float*)d_in[0];
    const float* W1   = (const float*)d_in[1];
    const float* b1   = (const float*)d_in[2];
    const float* W2   = (const float*)d_in[3];
    const float* b2   = (const float*)d_in[4];
    const void*  edges = d_in[5];
    float* out = (float*)d_out;

    char* ws = (char*)d_ws;
    const size_t SZ_N = 200704;  // >= 50001 ints
    int*   flag    = (int*)ws;                       // 256 B
    int*   partial = (int*)(ws + 256);               // 64 ints
    float* dinv    = (float*)(ws + 1024);
    int*   cnt     = (int*)(ws + 1024 + SZ_N);
    int*   off     = (int*)(ws + 1024 + 2 * SZ_N);
    int*   cursor  = (int*)(ws + 1024 + 3 * SZ_N);
    int2*  csr     = (int2*)(ws + 1024 + 4 * SZ_N);               // 6.4 MB
    float* H       = (float*)(ws + 1024 + 4 * SZ_N + (size_t)N_EDGES * 8);  // 12.8 MB

    const int NB_N = (N_NODES + 255) / 256;
    const int NB_E = (N_EDGES + 255) / 256;
    const int NB_G = (N_NODES + 63) / 64;
    const int NB_W = (N_NODES * 64 + 255) / 256;

    init_kernel<<<NB_N, 256, 0, stream>>>((const unsigned int*)edges, cnt, flag);
    deg_count<<<NB_E, 256, 0, stream>>>(edges, flag, cnt);
    scan_local<<<NCH, 1024, 0, stream>>>(cnt, off, partial, dinv);
    scan_mid<<<1, 64, 0, stream>>>(partial);
    scan_add<<<NCH, 1024, 0, stream>>>(off, partial, cursor);
    scatter_kernel<<<NB_E, 256, 0, stream>>>(edges, flag, dinv, cursor, csr);

    // Layer 1
    gemm_kernel<IN_DIM><<<NB_G, 256, 0, stream>>>(feat, W1, H);
    agg_csr<<<NB_W, 256, 0, stream>>>(H, dinv, b1, off, csr, out);

    // Layer 2 (out holds relu'd z1)
    gemm_kernel<OUT_DIM><<<NB_G, 256, 0, stream>>>(out, W2, H);
    agg_csr<<<NB_W, 256, 0, stream>>>(H, dinv, b2, off, csr, out);
}

// Round 5
// 208.171 us; speedup vs baseline: 7.6459x; 1.0058x over previous
//
#include <hip/hip_runtime.h>
#include <hip/hip_bf16.h>

#define N_NODES 50000
#define N_EDGES 800000
#define IN_DIM  256
#define OUT_DIM 64
#define NCH     49   // ceil(50000/1024) chunks for the scan

// ---------------------------------------------------------------------------
// init: zero cnt[]; block 0 probes edge dtype in parallel (256 threads).
// int64 little-endian values < 50000 -> every odd 32-bit word is 0.
// ---------------------------------------------------------------------------
__global__ void init_kernel(const unsigned int* __restrict__ e, int* __restrict__ cnt,
                            int* __restrict__ flag) {
    __shared__ int nz;
    if (threadIdx.x == 0) nz = 0;
    __syncthreads();
    if (blockIdx.x == 0) {
        unsigned int v = e[2 * threadIdx.x + 1];
        if (v != 0u) nz = 1;
    }
    __syncthreads();
    if (blockIdx.x == 0 && threadIdx.x == 0) flag[0] = (nz == 0) ? 1 : 0;
    int n = blockIdx.x * 256 + threadIdx.x;
    if (n < N_NODES) cnt[n] = 0;
}

__device__ __forceinline__ int load_idx(const void* edges, int is64, long long i) {
    if (is64) return (int)((const long long*)edges)[i];
    return ((const int*)edges)[i];
}

__global__ void deg_count(const void* __restrict__ edges, const int* __restrict__ flag,
                          int* __restrict__ cnt) {
    int e = blockIdx.x * 256 + threadIdx.x;
    if (e >= N_EDGES) return;
    int is64 = flag[0];
    int d = load_idx(edges, is64, (long long)N_EDGES + e);
    atomicAdd(&cnt[d], 1);
}

// --------------------- hierarchical exclusive scan -------------------------
__global__ __launch_bounds__(1024) void scan_local(const int* __restrict__ cnt,
                                                   int* __restrict__ off,
                                                   int* __restrict__ partial,
                                                   float* __restrict__ dinv) {
    __shared__ int smem[1024];
    int i = blockIdx.x * 1024 + threadIdx.x;
    int v = (i < N_NODES) ? cnt[i] : 0;
    if (i < N_NODES) dinv[i] = rsqrtf((float)(v + 1));
    smem[threadIdx.x] = v;
    __syncthreads();
    for (int s = 1; s < 1024; s <<= 1) {
        int t = 0;
        if (threadIdx.x >= s) t = smem[threadIdx.x - s];
        __syncthreads();
        if (threadIdx.x >= s) smem[threadIdx.x] += t;
        __syncthreads();
    }
    int incl = smem[threadIdx.x];
    if (i < N_NODES) off[i] = incl - v;
    if (threadIdx.x == 1023) partial[blockIdx.x] = incl;
}

__global__ void scan_mid(int* __restrict__ partial) {
    int lane = threadIdx.x;
    int v = (lane < NCH) ? partial[lane] : 0;
    int orig = v;
    for (int s = 1; s < 64; s <<= 1) {
        int t = __shfl_up(v, s);
        if (lane >= s) v += t;
    }
    if (lane < NCH) partial[lane] = v - orig;
    if (lane == 63) partial[63] = v;   // grand total
}

__global__ __launch_bounds__(1024) void scan_add(int* __restrict__ off,
                                                 const int* __restrict__ partial,
                                                 int* __restrict__ cursor) {
    int i = blockIdx.x * 1024 + threadIdx.x;
    if (i < N_NODES) {
        int o = off[i] + partial[blockIdx.x];
        off[i] = o;
        cursor[i] = o;
    }
    if (i == 0) off[N_NODES] = partial[63];
}

// Bucket edges by dst: csr[pos] = (src, norm)
__global__ void scatter_kernel(const void* __restrict__ edges, const int* __restrict__ flag,
                               const float* __restrict__ dinv, int* __restrict__ cursor,
                               int2* __restrict__ csr) {
    int e = blockIdx.x * 256 + threadIdx.x;
    if (e >= N_EDGES) return;
    int is64 = flag[0];
    int s = load_idx(edges, is64, e);
    int d = load_idx(edges, is64, (long long)N_EDGES + e);
    float norm = dinv[s] * dinv[d];
    int pos = atomicAdd(&cursor[d], 1);
    csr[pos] = make_int2(s, __float_as_int(norm));
}

// ---------------------------------------------------------------------------
// H[N,64] = X[N,K] @ W[K,64].
// 512 threads (8 waves), BM=64 rows/block -> grid 782, ~3 blocks/CU =
// 24 waves/CU (75% occ). Thread (cg=lane&15, rg=lane>>4, wave) owns
// 2 rows x 4 cols. W staged in LDS in KC=64 chunks (16 KB). Per 4-k step:
// 2 global b128 (X, 16-lane broadcast -> L1), 4 LDS b128 (free), 32 FMA.
// ---------------------------------------------------------------------------
#define FMA4(av, bv, ai)                                  \
    acc[ai][0] = fmaf(av, bv.x, acc[ai][0]);              \
    acc[ai][1] = fmaf(av, bv.y, acc[ai][1]);              \
    acc[ai][2] = fmaf(av, bv.z, acc[ai][2]);              \
    acc[ai][3] = fmaf(av, bv.w, acc[ai][3]);

template <int K>
__global__ __launch_bounds__(512) void gemm_kernel(const float* __restrict__ X,
                                                   const float* __restrict__ W,
                                                   float* __restrict__ H) {
    constexpr int KC = 64;
    __shared__ float wlds[KC][64];

    const int lane = threadIdx.x & 63;
    const int wave = threadIdx.x >> 6;
    const int cg = lane & 15;
    const int rg = lane >> 4;
    const int c0 = cg * 4;
    const int r0 = blockIdx.x * 64 + (wave * 4 + rg) * 2;

    const float* xrow[2];
#pragma unroll
    for (int i = 0; i < 2; ++i) {
        int r = r0 + i;
        if (r >= N_NODES) r = N_NODES - 1;   // clamp; stores guarded
        xrow[i] = X + (size_t)r * K;
    }

    float acc[2][4] = {};

    for (int kc = 0; kc < K; kc += KC) {
        __syncthreads();
        for (int idx = threadIdx.x; idx < KC * 16; idx += 512) {
            ((float4*)wlds)[idx] = ((const float4*)(W + kc * 64))[idx];
        }
        __syncthreads();

#pragma unroll 4
        for (int k = 0; k < KC; k += 4) {
            float4 a[2];
#pragma unroll
            for (int i = 0; i < 2; ++i) a[i] = *(const float4*)(xrow[i] + kc + k);
            float4 b0 = *(const float4*)&wlds[k + 0][c0];
            float4 b1 = *(const float4*)&wlds[k + 1][c0];
            float4 b2 = *(const float4*)&wlds[k + 2][c0];
            float4 b3 = *(const float4*)&wlds[k + 3][c0];
#pragma unroll
            for (int i = 0; i < 2; ++i) {
                FMA4(a[i].x, b0, i)
                FMA4(a[i].y, b1, i)
                FMA4(a[i].z, b2, i)
                FMA4(a[i].w, b3, i)
            }
        }
    }

#pragma unroll
    for (int i = 0; i < 2; ++i) {
        int r = r0 + i;
        if (r < N_NODES) {
            float4 o = make_float4(acc[i][0], acc[i][1], acc[i][2], acc[i][3]);
            *(float4*)&H[(size_t)r * 64 + c0] = o;
        }
    }
}

// ---------------------------------------------------------------------------
// Gather-aggregate: one wave per dst node, lane = column. Edges in batches
// of 8: 8 independent H-row loads in flight, then 8 FMAs.
// ---------------------------------------------------------------------------
__global__ __launch_bounds__(256) void agg_csr(const float* __restrict__ H,
                                               const float* __restrict__ dinv,
                                               const float* __restrict__ b,
                                               const int* __restrict__ off,
                                               const int2* __restrict__ csr,
                                               float* __restrict__ out) {
    int wid  = (blockIdx.x * 256 + threadIdx.x) >> 6;
    int lane = threadIdx.x & 63;
    if (wid >= N_NODES) return;
    float dd = dinv[wid];
    float acc = H[(size_t)wid * 64 + lane] * dd * dd + b[lane];
    int beg = off[wid], end = off[wid + 1];
    for (int k0 = beg; k0 < end; k0 += 64) {
        int myk = k0 + lane;
        int2 ev = (myk < end) ? csr[myk] : make_int2(0, 0);
        int cnt = min(64, end - k0);
        int i = 0;
        for (; i + 8 <= cnt; i += 8) {
            float v[8], nm[8];
#pragma unroll
            for (int jj = 0; jj < 8; ++jj) {
                int s  = __shfl(ev.x, i + jj);
                nm[jj] = __shfl(__int_as_float(ev.y), i + jj);
                v[jj]  = H[(size_t)s * 64 + lane];
            }
#pragma unroll
            for (int jj = 0; jj < 8; ++jj) acc = fmaf(v[jj], nm[jj], acc);
        }
        for (; i < cnt; ++i) {
            int   s  = __shfl(ev.x, i);
            float nm = __shfl(__int_as_float(ev.y), i);
            acc = fmaf(H[(size_t)s * 64 + lane], nm, acc);
        }
    }
    out[(size_t)wid * 64 + lane] = fmaxf(acc, 0.f);
}

extern "C" void kernel_launch(void* const* d_in, const int* in_sizes, int n_in,
                              void* d_out, int out_size, void* d_ws, size_t ws_size,
                              hipStream_t stream) {
    const float* feat = (const float*)d_in[0];
    const float* W1   = (const float*)d_in[1];
    const float* b1   = (const float*)d_in[2];
    const float* W2   = (const float*)d_in[3];
    const float* b2   = (const float*)d_in[4];
    const void*  edges = d_in[5];
    float* out = (float*)d_out;

    char* ws = (char*)d_ws;
    const size_t SZ_N = 200704;  // >= 50001 ints
    int*   flag    = (int*)ws;                       // 256 B
    int*   partial = (int*)(ws + 256);               // 64 ints
    float* dinv    = (float*)(ws + 1024);
    int*   cnt     = (int*)(ws + 1024 + SZ_N);
    int*   off     = (int*)(ws + 1024 + 2 * SZ_N);
    int*   cursor  = (int*)(ws + 1024 + 3 * SZ_N);
    int2*  csr     = (int2*)(ws + 1024 + 4 * SZ_N);               // 6.4 MB
    float* H       = (float*)(ws + 1024 + 4 * SZ_N + (size_t)N_EDGES * 8);  // 12.8 MB

    const int NB_N = (N_NODES + 255) / 256;
    const int NB_E = (N_EDGES + 255) / 256;
    const int NB_G = (N_NODES + 63) / 64;
    const int NB_W = (N_NODES * 64 + 255) / 256;

    init_kernel<<<NB_N, 256, 0, stream>>>((const unsigned int*)edges, cnt, flag);
    deg_count<<<NB_E, 256, 0, stream>>>(edges, flag, cnt);
    scan_local<<<NCH, 1024, 0, stream>>>(cnt, off, partial, dinv);
    scan_mid<<<1, 64, 0, stream>>>(partial);
    scan_add<<<NCH, 1024, 0, stream>>>(off, partial, cursor);
    scatter_kernel<<<NB_E, 256, 0, stream>>>(edges, flag, dinv, cursor, csr);

    // Layer 1
    gemm_kernel<IN_DIM><<<NB_G, 512, 0, stream>>>(feat, W1, H);
    agg_csr<<<NB_W, 256, 0, stream>>>(H, dinv, b1, off, csr, out);

    // Layer 2 (out holds relu'd z1)
    gemm_kernel<OUT_DIM><<<NB_G, 512, 0, stream>>>(out, W2, H);
    agg_csr<<<NB_W, 256, 0, stream>>>(H, dinv, b2, off, csr, out);
}